// Round 7
// baseline (225.793 us; speedup 1.0000x reference)
//
#include <hip/hip_runtime.h>
#include <hip/hip_cooperative_groups.h>

namespace cg = cooperative_groups;

#define NN 8192
#define FF 256
#define MM 128
#define HSLOTS 262144   // power of 2, 2x edge count
#define NTILES 2080     // 64*65/2 upper-tri 128x128 tiles

typedef __attribute__((ext_vector_type(8))) short bf16x8;
typedef __attribute__((ext_vector_type(4))) float f32x4;

// ws layout (bytes):
// [0, 16K): partial sums, 3 arrays x 64 slots, 64B apart
// [16K, +2MB): z bf16 [NN][MM]
// [.., +1MB): dedup hash set (u32 keys, 0 = empty; zeroed in phase 0)
// [.., +64KB): WmuT bf16 [MM][FF]   (transposed, K contiguous)
// [.., +64KB): WsgT bf16 [MM][FF]
#define P_KL    0
#define P_EDGE  (64 * 16)
#define P_SP    (128 * 16)
#define Z_OFF   16384
#define Z_BYTES (NN * MM * 2)
#define HASH_OFF (Z_OFF + Z_BYTES)
#define WT_OFF  (HASH_OFF + HSLOTS * 4)
#define WT_BYTES (MM * FF * 2)
#define XP_I4 33   // int4 pitch per x row (32 data + 1 pad)
#define XP_S  264

__device__ __forceinline__ float wave_reduce(float v) {
    #pragma unroll
    for (int off = 32; off > 0; off >>= 1) v += __shfl_down(v, off);
    return v;
}
__device__ __forceinline__ unsigned short f2bf(float f) {
    unsigned int u = __float_as_uint(f);
    u += 0x7fffu + ((u >> 16) & 1u);   // round to nearest even
    return (unsigned short)(u >> 16);
}
__device__ __forceinline__ int4 pack8(float4 a, float4 b) {
    int4 p;
    p.x = (int)f2bf(a.x) | ((int)f2bf(a.y) << 16);
    p.y = (int)f2bf(a.z) | ((int)f2bf(a.w) << 16);
    p.z = (int)f2bf(b.x) | ((int)f2bf(b.y) << 16);
    p.w = (int)f2bf(b.z) | ((int)f2bf(b.w) << 16);
    return p;
}
__device__ __forceinline__ float dotpair(unsigned int a, unsigned int b) {
    const float al = __uint_as_float(a << 16);
    const float ah = __uint_as_float(a & 0xffff0000u);
    const float bl = __uint_as_float(b << 16);
    const float bh = __uint_as_float(b & 0xffff0000u);
    return fmaf(al, bl, ah * bh);
}
__device__ __forceinline__ float aload(const float* p) {
    return __hip_atomic_load(p, __ATOMIC_RELAXED, __HIP_MEMORY_SCOPE_AGENT);
}

// ---- one cooperative megakernel: prep | enc | tiles+edges | combine ------
// Phases are uniform across blocks (no role branch); grid.sync() between
// dependent phases replaces 3 launch gaps; round-2's proven tile inner loop.
__global__ __launch_bounds__(256, 3)
void mega_kernel(const float* __restrict__ x, const float* __restrict__ eps,
                 const float* __restrict__ Wmu, const float* __restrict__ Wsg,
                 const float* __restrict__ bmu, const float* __restrict__ bsg,
                 const int* __restrict__ ei, int E,
                 unsigned short* __restrict__ WmuT,
                 unsigned short* __restrict__ WsgT,
                 unsigned short* __restrict__ zb,
                 unsigned int* __restrict__ ht,
                 float* __restrict__ part, float* __restrict__ out) {
    __shared__ int4 la[128 * 8];    // 16 KB (tile A / encoder x-stage)
    __shared__ int4 lb[128 * 8];    // 16 KB (tile B)
    __shared__ float red[4];

    cg::grid_group grid = cg::this_grid();
    const int tid = threadIdx.x;
    const int bid = blockIdx.x;
    const int nb  = gridDim.x;
    const int wid = tid >> 6, lane = tid & 63;
    const int l15 = lane & 15, quad = lane >> 4;

    // ================= phase 0: W transpose->bf16, zero part + hash =======
    for (int u = bid; u < 128; u += nb) {
        const int t = u * 256 + tid;              // 0..32767
        const int n = t >> 8, f = t & 255;
        WmuT[t] = f2bf(Wmu[f * MM + n]);
        WsgT[t] = f2bf(Wsg[f * MM + n]);
        if (t < 4096) part[t] = 0.f;
        uint4 z4 = {0u, 0u, 0u, 0u};
        ((uint4*)ht)[t * 2]     = z4;             // 65536 uint4 = 1 MB
        ((uint4*)ht)[t * 2 + 1] = z4;
    }
    grid.sync();

    // ================= phase 1: encoder (16 rows per unit, 512 units) =====
    for (int u = bid; u < NN / 16; u += nb) {
        const int row0 = u * 16;
        __syncthreads();   // protect la across loop iterations
        {   // stage 16 rows x 256 cols of x as bf16
            const int r = tid >> 4, ch = tid & 15;
            const float4* g0 = (const float4*)(x + (size_t)(row0 + r) * FF + ch * 8);
            const float4* g1 = (const float4*)(x + (size_t)(row0 + r) * FF + (ch + 16) * 8);
            ((int4*)la)[r * XP_I4 + ch]      = pack8(g0[0], g0[1]);
            ((int4*)la)[r * XP_I4 + ch + 16] = pack8(g1[0], g1[1]);
        }
        __syncthreads();

        const short* sax = (const short*)la;
        const int4* wtm = (const int4*)WmuT;      // row n = 32 int4 (K=256)
        const int4* wts = (const int4*)WsgT;

        f32x4 zero4 = {0.f, 0.f, 0.f, 0.f};
        f32x4 accm[2], accl[2];
        accm[0] = accm[1] = accl[0] = accl[1] = zero4;

        #pragma unroll
        for (int ks = 0; ks < 8; ++ks) {          // K = 8 x 32
            const bf16x8 a = *(const bf16x8*)&sax[l15 * XP_S + ks * 32 + quad * 8];
            #pragma unroll
            for (int j = 0; j < 2; ++j) {
                const int n = wid * 32 + j * 16 + l15;
                const bf16x8 bmf = *(const bf16x8*)&wtm[n * 32 + ks * 4 + quad];
                const bf16x8 bsf = *(const bf16x8*)&wts[n * 32 + ks * 4 + quad];
                accm[j] = __builtin_amdgcn_mfma_f32_16x16x32_bf16(a, bmf, accm[j], 0, 0, 0);
                accl[j] = __builtin_amdgcn_mfma_f32_16x16x32_bf16(a, bsf, accl[j], 0, 0, 0);
            }
        }

        // epilogue: C map col=lane&15, row=quad*4+reg [m89]
        float klp = 0.f;
        #pragma unroll
        for (int j = 0; j < 2; ++j) {
            const int col = wid * 32 + j * 16 + l15;
            const float bm = bmu[col], bs = bsg[col];
            #pragma unroll
            for (int r = 0; r < 4; ++r) {
                const int row = row0 + quad * 4 + r;
                const float mu = accm[j][r] + bm;
                const float ls = accl[j][r] + bs;
                const float sg = __expf(ls);
                const float zz = fmaf(sg, eps[(size_t)row * MM + col], mu);
                zb[(size_t)row * MM + col] = f2bf(zz);
                klp += 0.5f * (sg * sg + mu * mu - 1.f) - ls;
            }
        }

        klp = wave_reduce(klp);
        if (lane == 0) red[wid] = klp;
        __syncthreads();
        if (tid == 0)
            atomicAdd(&part[P_KL + (u & 63) * 16],
                      red[0] + red[1] + red[2] + red[3]);
    }
    grid.sync();

    // ================= phase 2a: z@z^T upper-tri tiles (round-2 loop) =====
    const int wm = wid >> 1, wn = wid & 1;
    const int xk = l15 & 7;                       // xor key for fragment reads
    const short* sa = (const short*)la;
    const short* sb = (const short*)lb;

    for (int t = bid; t < NTILES; t += nb) {
        // triangular map: t -> (bi<=bj) over 64x64 tile grid
        int bi = (int)((129.0f - sqrtf(16641.0f - 8.0f * (float)t)) * 0.5f);
        bi = min(max(bi, 0), 63);
        while ((bi * (129 - bi)) / 2 > t) --bi;
        while (((bi + 1) * (128 - bi)) / 2 <= t) ++bi;
        const int bj = bi + (t - (bi * (129 - bi)) / 2);

        const int4* ga = (const int4*)(zb + (size_t)bi * 128 * MM);
        const int4* gb = (const int4*)(zb + (size_t)bj * 128 * MM);

        f32x4 zero4 = {0.f, 0.f, 0.f, 0.f};
        f32x4 acc[4][4];
        #pragma unroll
        for (int i = 0; i < 4; ++i)
            #pragma unroll
            for (int j = 0; j < 4; ++j) acc[i][j] = zero4;

        #pragma unroll
        for (int kc = 0; kc < 2; ++kc) {          // K halves of 64
            __syncthreads();                      // la/lb safe to overwrite
            #pragma unroll
            for (int i = 0; i < 4; ++i) {         // stage both tiles, swizzled
                const int c = tid + i * 256;      // 0..1023
                const int row = c >> 3, ch = c & 7;
                const int sl = ch ^ (row & 7);
                la[row * 8 + sl] = ga[row * 16 + kc * 8 + ch];
                lb[row * 8 + sl] = gb[row * 16 + kc * 8 + ch];
            }
            __syncthreads();
            #pragma unroll
            for (int ks = 0; ks < 2; ++ks) {      // two k=32 MFMA steps
                const int kq = ks * 4 + quad;
                bf16x8 af[4], bfr[4];
                #pragma unroll
                for (int t2 = 0; t2 < 4; ++t2) {
                    const int ar = wm * 64 + t2 * 16 + l15;
                    af[t2]  = *(const bf16x8*)&sa[ar * 64 + ((kq ^ xk) * 8)];
                    const int br = wn * 64 + t2 * 16 + l15;
                    bfr[t2] = *(const bf16x8*)&sb[br * 64 + ((kq ^ xk) * 8)];
                }
                #pragma unroll
                for (int i = 0; i < 4; ++i)
                    #pragma unroll
                    for (int j = 0; j < 4; ++j)
                        acc[i][j] = __builtin_amdgcn_mfma_f32_16x16x32_bf16(
                            af[i], bfr[j], acc[i][j], 0, 0, 0);
            }
        }

        // softplus(v) ~= max(v,0) + e - e^2/2, e=exp(-|v|); err <= e^3/3
        float tsum = 0.f;
        if (bi != bj) {
            #pragma unroll
            for (int i = 0; i < 4; ++i)
                #pragma unroll
                for (int j = 0; j < 4; ++j)
                    #pragma unroll
                    for (int r = 0; r < 4; ++r) {
                        const float v = acc[i][j][r];
                        const float e = __expf(-fabsf(v));
                        tsum += fmaxf(v, 0.f) + e * fmaf(e, -0.5f, 1.f);
                    }
        } else {
            const int rbase = wm * 64 + quad * 4;
            const int cbase = wn * 64 + l15;
            #pragma unroll
            for (int i = 0; i < 4; ++i)
                #pragma unroll
                for (int j = 0; j < 4; ++j)
                    #pragma unroll
                    for (int r = 0; r < 4; ++r)
                        if (cbase + j * 16 > rbase + i * 16 + r) {
                            const float v = acc[i][j][r];
                            const float e = __expf(-fabsf(v));
                            tsum += fmaxf(v, 0.f) + e * fmaf(e, -0.5f, 1.f);
                        }
        }

        tsum = wave_reduce(tsum);
        if (lane == 0)
            atomicAdd(&part[P_SP + ((bi * 64 + bj + wid * 16) & 63) * 16], tsum);
    }

    // ================= phase 2b: edges, 64 per wave -----------------------
    // waves assigned from HIGH block ids (they got fewer tiles) for balance
    const int gw = (nb - 1 - bid) * 4 + wid;
    for (int w = gw; w < (E >> 6); w += nb * 4) {
        const int e = w * 64 + lane;              // coalesced edge reads
        float contrib = 0.f;
        if (e < E) {
            const int i = ei[e];
            const int j = ei[E + e];
            if (i != j) {
                const int a = min(i, j), b = max(i, j);
                // speculative row loads + dot overlap the CAS round-trip
                const uint4* za = (const uint4*)(zb + (size_t)a * MM);
                const uint4* zc = (const uint4*)(zb + (size_t)b * MM);
                float s = 0.f;
                #pragma unroll
                for (int q = 0; q < MM / 8; ++q) {
                    const uint4 ua = za[q], ub = zc[q];
                    s += dotpair(ua.x, ub.x) + dotpair(ua.y, ub.y)
                       + dotpair(ua.z, ub.z) + dotpair(ua.w, ub.w);
                }
                const unsigned int key = (unsigned int)a * NN + b;  // >=1
                unsigned int slot = (key * 2654435761u) & (HSLOTS - 1);
                bool first = false;
                for (;;) {
                    const unsigned int old = atomicCAS(&ht[slot], 0u, key);
                    if (old == 0u) { first = true; break; }
                    if (old == key) break;
                    slot = (slot + 1) & (HSLOTS - 1);
                }
                if (first) contrib = s;
            }
        }
        contrib = wave_reduce(contrib);
        if (lane == 0)
            atomicAdd(&part[P_EDGE + (w & 63) * 16], contrib);
    }
    grid.sync();

    // ================= phase 3: combine ===================================
    if (bid == 0 && tid < 64) {
        float v = aload(&part[P_SP + tid * 16])
                - aload(&part[P_EDGE + tid * 16])
                + 0.001f * aload(&part[P_KL + tid * 16]);
        v = wave_reduce(v);
        if (tid == 0) out[0] = v;
    }
}

extern "C" void kernel_launch(void* const* d_in, const int* in_sizes, int n_in,
                              void* d_out, int out_size, void* d_ws, size_t ws_size,
                              hipStream_t stream) {
    const float* x   = (const float*)d_in[0];
    const int* ei    = (const int*)d_in[1];     // int32 on device
    const float* eps = (const float*)d_in[2];
    const float* Wmu = (const float*)d_in[3];
    const float* bmu = (const float*)d_in[4];
    const float* Wsg = (const float*)d_in[5];
    const float* bsg = (const float*)d_in[6];
    float* out = (float*)d_out;
    char* ws = (char*)d_ws;

    float* part = (float*)ws;
    unsigned short* zb = (unsigned short*)(ws + Z_OFF);
    unsigned int* ht = (unsigned int*)(ws + HASH_OFF);
    unsigned short* WmuT = (unsigned short*)(ws + WT_OFF);
    unsigned short* WsgT = (unsigned short*)(ws + WT_OFF + WT_BYTES);
    int E = in_sizes[1] / 2;

    int maxb = 0;
    if (hipOccupancyMaxActiveBlocksPerMultiprocessor(&maxb, mega_kernel, 256, 0)
            != hipSuccess || maxb < 1)
        maxb = 2;                                  // conservative fallback
    int grid = maxb * 256;                         // 256 CUs on MI355X
    if (grid > 768) grid = 768;                    // >= encoder/edge needs

    void* args[] = {(void*)&x, (void*)&eps, (void*)&Wmu, (void*)&Wsg,
                    (void*)&bmu, (void*)&bsg, (void*)&ei, (void*)&E,
                    (void*)&WmuT, (void*)&WsgT, (void*)&zb, (void*)&ht,
                    (void*)&part, (void*)&out};
    hipLaunchCooperativeKernel((const void*)mega_kernel, dim3(grid), dim3(256),
                               args, 0, stream);
}

// Round 8
// 204.078 us; speedup vs baseline: 1.1064x; 1.1064x over previous
//
#include <hip/hip_runtime.h>

#define NN 8192
#define FF 256
#define MM 128
#define HSLOTS 262144   // power of 2, 2x edge count
#define NT2 528         // 32*33/2 upper-tri 256x256 tiles

typedef __attribute__((ext_vector_type(8))) short bf16x8;
typedef __attribute__((ext_vector_type(4))) float f32x4;

// ws layout (bytes):
// [0, 16K): partial sums, 3 arrays x 64 slots, 64B apart
// [16K, +2MB): z bf16 [NN][MM]
// [.., +1MB): dedup hash set (u32 keys, 0 = empty; zeroed in prep_w)
// [.., +64KB): WmuT bf16 [MM][FF]   (transposed, K contiguous)
// [.., +64KB): WsgT bf16 [MM][FF]
#define P_KL    0
#define P_EDGE  (64 * 16)
#define P_SP    (128 * 16)
#define Z_OFF   16384
#define Z_BYTES (NN * MM * 2)
#define HASH_OFF (Z_OFF + Z_BYTES)
#define WT_OFF  (HASH_OFF + HSLOTS * 4)
#define WT_BYTES (MM * FF * 2)

__device__ __forceinline__ float wave_reduce(float v) {
    #pragma unroll
    for (int off = 32; off > 0; off >>= 1) v += __shfl_down(v, off);
    return v;
}
__device__ __forceinline__ unsigned short f2bf(float f) {
    unsigned int u = __float_as_uint(f);
    u += 0x7fffu + ((u >> 16) & 1u);   // round to nearest even
    return (unsigned short)(u >> 16);
}
__device__ __forceinline__ int4 pack8(float4 a, float4 b) {
    int4 p;
    p.x = (int)f2bf(a.x) | ((int)f2bf(a.y) << 16);
    p.y = (int)f2bf(a.z) | ((int)f2bf(a.w) << 16);
    p.z = (int)f2bf(b.x) | ((int)f2bf(b.y) << 16);
    p.w = (int)f2bf(b.z) | ((int)f2bf(b.w) << 16);
    return p;
}

// ---- prep: W transpose->bf16, zero partials, zero hash table -------------
__global__ __launch_bounds__(256)
void prep_w(const float* __restrict__ Wmu, const float* __restrict__ Wsg,
            unsigned short* __restrict__ WmuT, unsigned short* __restrict__ WsgT,
            float* __restrict__ part, unsigned int* __restrict__ ht) {
    const int t = blockIdx.x * 256 + threadIdx.x;   // 0..32767
    const int n = t >> 8, f = t & 255;
    WmuT[t] = f2bf(Wmu[f * MM + n]);
    WsgT[t] = f2bf(Wsg[f * MM + n]);
    if (t < 4096) part[t] = 0.f;          // 16 KB of partial slots
    uint4 z4 = {0u, 0u, 0u, 0u};
    ((uint4*)ht)[t * 2]     = z4;         // 32768*2 uint4 = 262144 words
    ((uint4*)ht)[t * 2 + 1] = z4;
}

// ---- encoder: MFMA GEMMs, W-fragments direct from global, 1 barrier ------
#define XP_I4 33   // int4 pitch per x row (32 data + 1 pad)
#define XP_S  264

__global__ __launch_bounds__(256)
void encoder_mfma(const float* __restrict__ x, const float* __restrict__ eps,
                  const unsigned short* __restrict__ WmuT,
                  const unsigned short* __restrict__ WsgT,
                  const float* __restrict__ bmu, const float* __restrict__ bsg,
                  unsigned short* __restrict__ zb, float* __restrict__ part) {
    __shared__ int4 ax[16 * XP_I4];   // 8.4 KB: 16 x-rows, K=256 bf16
    __shared__ float red[4];
    const int tid = threadIdx.x;
    const int wid = tid >> 6, lane = tid & 63;
    const int l15 = lane & 15, quad = lane >> 4;
    const int row0 = blockIdx.x * 16;

    {   // stage 16 rows x 256 cols of x as bf16 (coalesced float4 pairs)
        const int r = tid >> 4, ch = tid & 15;
        const float4* g0 = (const float4*)(x + (size_t)(row0 + r) * FF + ch * 8);
        const float4* g1 = (const float4*)(x + (size_t)(row0 + r) * FF + (ch + 16) * 8);
        ax[r * XP_I4 + ch]      = pack8(g0[0], g0[1]);
        ax[r * XP_I4 + ch + 16] = pack8(g1[0], g1[1]);
    }
    __syncthreads();

    const short* sax = (const short*)ax;
    const int4* wtm = (const int4*)WmuT;   // row n = 32 int4 (K=256)
    const int4* wts = (const int4*)WsgT;

    f32x4 zero4 = {0.f, 0.f, 0.f, 0.f};
    f32x4 accm[2], accl[2];
    accm[0] = accm[1] = accl[0] = accl[1] = zero4;

    #pragma unroll
    for (int ks = 0; ks < 8; ++ks) {       // K = 8 x 32
        const bf16x8 a = *(const bf16x8*)&sax[l15 * XP_S + ks * 32 + quad * 8];
        #pragma unroll
        for (int j = 0; j < 2; ++j) {
            const int n = wid * 32 + j * 16 + l15;
            const bf16x8 bmf = *(const bf16x8*)&wtm[n * 32 + ks * 4 + quad];
            const bf16x8 bsf = *(const bf16x8*)&wts[n * 32 + ks * 4 + quad];
            accm[j] = __builtin_amdgcn_mfma_f32_16x16x32_bf16(a, bmf, accm[j], 0, 0, 0);
            accl[j] = __builtin_amdgcn_mfma_f32_16x16x32_bf16(a, bsf, accl[j], 0, 0, 0);
        }
    }

    // epilogue: C map col=lane&15, row=quad*4+reg [m89]
    float klp = 0.f;
    #pragma unroll
    for (int j = 0; j < 2; ++j) {
        const int col = wid * 32 + j * 16 + l15;
        const float bm = bmu[col], bs = bsg[col];
        #pragma unroll
        for (int r = 0; r < 4; ++r) {
            const int row = row0 + quad * 4 + r;
            const float mu = accm[j][r] + bm;
            const float ls = accl[j][r] + bs;
            const float sg = __expf(ls);
            const float zz = fmaf(sg, eps[(size_t)row * MM + col], mu);
            zb[(size_t)row * MM + col] = f2bf(zz);
            klp += 0.5f * (sg * sg + mu * mu - 1.f) - ls;
        }
    }

    klp = wave_reduce(klp);
    if (lane == 0) red[wid] = klp;
    __syncthreads();
    if (tid == 0)
        atomicAdd(&part[P_KL + (blockIdx.x & 63) * 16],
                  red[0] + red[1] + red[2] + red[3]);
}

// ---- helpers for edge tail ----------------------------------------------
__device__ __forceinline__ float dotpair(unsigned int a, unsigned int b) {
    const float al = __uint_as_float(a << 16);
    const float ah = __uint_as_float(a & 0xffff0000u);
    const float bl = __uint_as_float(b << 16);
    const float bh = __uint_as_float(b & 0xffff0000u);
    return fmaf(al, bl, ah * bh);
}

// ---- tile+edge: 256x256 upper-tri z@z^T tiles, 512 threads (8 waves of ---
// 64x128 output). K=128 is only 2 K-steps, so per-block prologue/epilogue
// dominated the 128^2 version; 256^2 quarters the block count and halves
// staging bytes per output. Blocks [0,256) also handle 1 edge per thread.
__global__ __launch_bounds__(512, 4)
void tile_edge_kernel(const unsigned short* __restrict__ zb,
                      const int* __restrict__ ei, int E,
                      unsigned int* __restrict__ ht,
                      float* __restrict__ part) {
    // XOR-swizzled unpadded LDS: tile = 256 rows x 8 int4 (BK=64), chunk ch
    // of row r stored at slot ch^(r&7). 2 tiles x 32 KB = 64 KB -> 2 blk/CU.
    __shared__ int4 la[256 * 8];
    __shared__ int4 lb[256 * 8];

    const int tid = threadIdx.x;
    const int bid = blockIdx.x;

    // triangular map: bid -> (bi<=bj) over 32x32 tile grid
    // off(bi) = bi*(65-bi)/2 ; row bi holds 32-bi tiles
    int bi = (int)((65.0f - sqrtf(4225.0f - 8.0f * (float)bid)) * 0.5f);
    bi = min(max(bi, 0), 31);
    while ((bi * (65 - bi)) / 2 > bid) --bi;
    while (((bi + 1) * (64 - bi)) / 2 <= bid) ++bi;
    const int bj = bi + (bid - (bi * (65 - bi)) / 2);

    const int wid = tid >> 6, lane = tid & 63;
    const int wr = wid >> 1, wc = wid & 1;      // 4x2 wave grid, 64x128 each
    const int l15 = lane & 15, quad = lane >> 4;
    const int xk = l15 & 7;                     // xor key for fragment reads

    const int4* ga = (const int4*)(zb + (size_t)bi * 256 * MM);
    const int4* gb = (const int4*)(zb + (size_t)bj * 256 * MM);

    f32x4 zero4 = {0.f, 0.f, 0.f, 0.f};
    f32x4 acc[4][8];
    #pragma unroll
    for (int i = 0; i < 4; ++i)
        #pragma unroll
        for (int j = 0; j < 8; ++j) acc[i][j] = zero4;

    const short* sa = (const short*)la;
    const short* sb = (const short*)lb;

    #pragma unroll
    for (int kc = 0; kc < 2; ++kc) {        // K halves of 64
        if (kc) __syncthreads();
        #pragma unroll
        for (int i = 0; i < 4; ++i) {       // stage both tiles, swizzled
            const int c = tid + i * 512;    // 0..2047
            const int row = c >> 3, ch = c & 7;
            const int sl = ch ^ (row & 7);
            la[row * 8 + sl] = ga[row * 16 + kc * 8 + ch];
            lb[row * 8 + sl] = gb[row * 16 + kc * 8 + ch];
        }
        __syncthreads();
        #pragma unroll
        for (int ks = 0; ks < 2; ++ks) {    // two k=32 MFMA steps
            const int kq = ks * 4 + quad;   // chunk index 0..7 (int4 units)
            bf16x8 af[4], bfr[8];
            #pragma unroll
            for (int t2 = 0; t2 < 4; ++t2) {
                const int ar = wr * 64 + t2 * 16 + l15;
                af[t2] = *(const bf16x8*)&sa[ar * 64 + ((kq ^ xk) * 8)];
            }
            #pragma unroll
            for (int t2 = 0; t2 < 8; ++t2) {
                const int br = wc * 128 + t2 * 16 + l15;
                bfr[t2] = *(const bf16x8*)&sb[br * 64 + ((kq ^ xk) * 8)];
            }
            #pragma unroll
            for (int i = 0; i < 4; ++i)
                #pragma unroll
                for (int j = 0; j < 8; ++j)
                    acc[i][j] = __builtin_amdgcn_mfma_f32_16x16x32_bf16(
                        af[i], bfr[j], acc[i][j], 0, 0, 0);
        }
    }

    // softplus(v) ~= max(v,0) + e - e^2/2, e=exp(-|v|); err <= e^3/3,
    // summed bound ~1e5 << threshold
    float tsum = 0.f;
    if (bi != bj) {
        #pragma unroll
        for (int i = 0; i < 4; ++i)
            #pragma unroll
            for (int j = 0; j < 8; ++j)
                #pragma unroll
                for (int r = 0; r < 4; ++r) {
                    const float v = acc[i][j][r];
                    const float e = __expf(-fabsf(v));
                    tsum += fmaxf(v, 0.f) + e * fmaf(e, -0.5f, 1.f);
                }
    } else {
        const int rbase = wr * 64 + quad * 4;
        const int cbase = wc * 128 + l15;
        #pragma unroll
        for (int i = 0; i < 4; ++i)
            #pragma unroll
            for (int j = 0; j < 8; ++j)
                #pragma unroll
                for (int r = 0; r < 4; ++r)
                    if (cbase + j * 16 > rbase + i * 16 + r) {
                        const float v = acc[i][j][r];
                        const float e = __expf(-fabsf(v));
                        tsum += fmaxf(v, 0.f) + e * fmaf(e, -0.5f, 1.f);
                    }
    }

    tsum = wave_reduce(tsum);
    if (lane == 0)   // per-wave atomic: no barrier needed
        atomicAdd(&part[P_SP + ((bi * 64 + bj + wid * 16) & 63) * 16], tsum);

    // ---- edge tail: blocks [0,256), one edge per thread (256*512 = E) ----
    if (bid < (E >> 9)) {
        const int e = bid * 512 + tid;
        float contrib = 0.f;
        const int i = ei[e];
        const int j = ei[E + e];
        if (i != j) {
            const int a = min(i, j), b = max(i, j);
            const unsigned int key = (unsigned int)a * NN + b;  // >=1, <2^26
            unsigned int slot = (key * 2654435761u) & (HSLOTS - 1);
            bool first = false;
            for (;;) {
                const unsigned int old = atomicCAS(&ht[slot], 0u, key);
                if (old == 0u) { first = true; break; }
                if (old == key) break;
                slot = (slot + 1) & (HSLOTS - 1);
            }
            if (first) {
                const uint4* za = (const uint4*)(zb + (size_t)a * MM);
                const uint4* zc = (const uint4*)(zb + (size_t)b * MM);
                float s = 0.f;
                #pragma unroll
                for (int q = 0; q < MM / 8; ++q) {
                    const uint4 ua = za[q], ub = zc[q];
                    s += dotpair(ua.x, ub.x) + dotpair(ua.y, ub.y)
                       + dotpair(ua.z, ub.z) + dotpair(ua.w, ub.w);
                }
                contrib = s;
            }
        }
        contrib = wave_reduce(contrib);
        if (lane == 0)
            atomicAdd(&part[P_EDGE + (bid & 63) * 16], contrib);
    }
}

// ---- final combine: sum 3 x 64 partial slots ----------------------------
__global__ void combine_kernel(const float* __restrict__ part,
                               float* __restrict__ out) {
    const int t = threadIdx.x;   // 64 threads
    float v = part[P_SP + t * 16] - part[P_EDGE + t * 16]
            + 0.001f * part[P_KL + t * 16];
    v = wave_reduce(v);
    if (t == 0) out[0] = v;
}

extern "C" void kernel_launch(void* const* d_in, const int* in_sizes, int n_in,
                              void* d_out, int out_size, void* d_ws, size_t ws_size,
                              hipStream_t stream) {
    const float* x   = (const float*)d_in[0];
    const int* ei    = (const int*)d_in[1];     // int32 on device
    const float* eps = (const float*)d_in[2];
    const float* Wmu = (const float*)d_in[3];
    const float* bmu = (const float*)d_in[4];
    const float* Wsg = (const float*)d_in[5];
    const float* bsg = (const float*)d_in[6];
    float* out = (float*)d_out;
    char* ws = (char*)d_ws;

    float* part = (float*)ws;
    unsigned short* zb = (unsigned short*)(ws + Z_OFF);
    unsigned int* ht = (unsigned int*)(ws + HASH_OFF);
    unsigned short* WmuT = (unsigned short*)(ws + WT_OFF);
    unsigned short* WsgT = (unsigned short*)(ws + WT_OFF + WT_BYTES);
    const int E = in_sizes[1] / 2;

    prep_w<<<128, 256, 0, stream>>>(Wmu, Wsg, WmuT, WsgT, part, ht);
    encoder_mfma<<<NN / 16, 256, 0, stream>>>(x, eps, WmuT, WsgT, bmu, bsg, zb, part);
    tile_edge_kernel<<<NT2, 512, 0, stream>>>(zb, ei, E, ht, part);
    combine_kernel<<<1, 64, 0, stream>>>(part, out);
}

// Round 9
// 120.765 us; speedup vs baseline: 1.8697x; 1.6899x over previous
//
#include <hip/hip_runtime.h>

#define NN 8192
#define FF 256
#define MM 128
#define HSLOTS 262144   // power of 2, 2x edge count
#define NT2 528         // 32*33/2 upper-tri 256x256 tiles

typedef __attribute__((ext_vector_type(8))) short bf16x8;
typedef __attribute__((ext_vector_type(4))) float f32x4;

// ws layout (bytes):
// [0, 16K): partial sums, 3 arrays x 64 slots, 64B apart
// [16K, +2MB): z bf16 [NN][MM]
// [.., +1MB): dedup hash set (u32 keys, 0 = empty; zeroed in prep_w)
// [.., +64KB): WmuT bf16 [MM][FF]   (transposed, K contiguous)
// [.., +64KB): WsgT bf16 [MM][FF]
#define P_KL    0
#define P_EDGE  (64 * 16)
#define P_SP    (128 * 16)
#define Z_OFF   16384
#define Z_BYTES (NN * MM * 2)
#define HASH_OFF (Z_OFF + Z_BYTES)
#define WT_OFF  (HASH_OFF + HSLOTS * 4)
#define WT_BYTES (MM * FF * 2)

__device__ __forceinline__ float wave_reduce(float v) {
    #pragma unroll
    for (int off = 32; off > 0; off >>= 1) v += __shfl_down(v, off);
    return v;
}
__device__ __forceinline__ unsigned short f2bf(float f) {
    unsigned int u = __float_as_uint(f);
    u += 0x7fffu + ((u >> 16) & 1u);   // round to nearest even
    return (unsigned short)(u >> 16);
}
__device__ __forceinline__ int4 pack8(float4 a, float4 b) {
    int4 p;
    p.x = (int)f2bf(a.x) | ((int)f2bf(a.y) << 16);
    p.y = (int)f2bf(a.z) | ((int)f2bf(a.w) << 16);
    p.z = (int)f2bf(b.x) | ((int)f2bf(b.y) << 16);
    p.w = (int)f2bf(b.z) | ((int)f2bf(b.w) << 16);
    return p;
}

// ---- prep: W transpose->bf16, zero partials, zero hash table -------------
__global__ __launch_bounds__(256)
void prep_w(const float* __restrict__ Wmu, const float* __restrict__ Wsg,
            unsigned short* __restrict__ WmuT, unsigned short* __restrict__ WsgT,
            float* __restrict__ part, unsigned int* __restrict__ ht) {
    const int t = blockIdx.x * 256 + threadIdx.x;   // 0..32767
    const int n = t >> 8, f = t & 255;
    WmuT[t] = f2bf(Wmu[f * MM + n]);
    WsgT[t] = f2bf(Wsg[f * MM + n]);
    if (t < 4096) part[t] = 0.f;          // 16 KB of partial slots
    uint4 z4 = {0u, 0u, 0u, 0u};
    ((uint4*)ht)[t * 2]     = z4;         // 32768*2 uint4 = 262144 words
    ((uint4*)ht)[t * 2 + 1] = z4;
}

// ---- encoder: MFMA GEMMs, W-fragments direct from global, 1 barrier ------
#define XP_I4 33   // int4 pitch per x row (32 data + 1 pad)
#define XP_S  264

__global__ __launch_bounds__(256)
void encoder_mfma(const float* __restrict__ x, const float* __restrict__ eps,
                  const unsigned short* __restrict__ WmuT,
                  const unsigned short* __restrict__ WsgT,
                  const float* __restrict__ bmu, const float* __restrict__ bsg,
                  unsigned short* __restrict__ zb, float* __restrict__ part) {
    __shared__ int4 ax[16 * XP_I4];   // 8.4 KB: 16 x-rows, K=256 bf16
    __shared__ float red[4];
    const int tid = threadIdx.x;
    const int wid = tid >> 6, lane = tid & 63;
    const int l15 = lane & 15, quad = lane >> 4;
    const int row0 = blockIdx.x * 16;

    {   // stage 16 rows x 256 cols of x as bf16 (coalesced float4 pairs)
        const int r = tid >> 4, ch = tid & 15;
        const float4* g0 = (const float4*)(x + (size_t)(row0 + r) * FF + ch * 8);
        const float4* g1 = (const float4*)(x + (size_t)(row0 + r) * FF + (ch + 16) * 8);
        ax[r * XP_I4 + ch]      = pack8(g0[0], g0[1]);
        ax[r * XP_I4 + ch + 16] = pack8(g1[0], g1[1]);
    }
    __syncthreads();

    const short* sax = (const short*)ax;
    const int4* wtm = (const int4*)WmuT;   // row n = 32 int4 (K=256)
    const int4* wts = (const int4*)WsgT;

    f32x4 zero4 = {0.f, 0.f, 0.f, 0.f};
    f32x4 accm[2], accl[2];
    accm[0] = accm[1] = accl[0] = accl[1] = zero4;

    #pragma unroll
    for (int ks = 0; ks < 8; ++ks) {       // K = 8 x 32
        const bf16x8 a = *(const bf16x8*)&sax[l15 * XP_S + ks * 32 + quad * 8];
        #pragma unroll
        for (int j = 0; j < 2; ++j) {
            const int n = wid * 32 + j * 16 + l15;
            const bf16x8 bmf = *(const bf16x8*)&wtm[n * 32 + ks * 4 + quad];
            const bf16x8 bsf = *(const bf16x8*)&wts[n * 32 + ks * 4 + quad];
            accm[j] = __builtin_amdgcn_mfma_f32_16x16x32_bf16(a, bmf, accm[j], 0, 0, 0);
            accl[j] = __builtin_amdgcn_mfma_f32_16x16x32_bf16(a, bsf, accl[j], 0, 0, 0);
        }
    }

    // epilogue: C map col=lane&15, row=quad*4+reg [m89]
    float klp = 0.f;
    #pragma unroll
    for (int j = 0; j < 2; ++j) {
        const int col = wid * 32 + j * 16 + l15;
        const float bm = bmu[col], bs = bsg[col];
        #pragma unroll
        for (int r = 0; r < 4; ++r) {
            const int row = row0 + quad * 4 + r;
            const float mu = accm[j][r] + bm;
            const float ls = accl[j][r] + bs;
            const float sg = __expf(ls);
            const float zz = fmaf(sg, eps[(size_t)row * MM + col], mu);
            zb[(size_t)row * MM + col] = f2bf(zz);
            klp += 0.5f * (sg * sg + mu * mu - 1.f) - ls;
        }
    }

    klp = wave_reduce(klp);
    if (lane == 0) red[wid] = klp;
    __syncthreads();
    if (tid == 0)
        atomicAdd(&part[P_KL + (blockIdx.x & 63) * 16],
                  red[0] + red[1] + red[2] + red[3]);
}

// ---- helpers for edge tail ----------------------------------------------
__device__ __forceinline__ float dotpair(unsigned int a, unsigned int b) {
    const float al = __uint_as_float(a << 16);
    const float ah = __uint_as_float(a & 0xffff0000u);
    const float bl = __uint_as_float(b << 16);
    const float bh = __uint_as_float(b & 0xffff0000u);
    return fmaf(al, bl, ah * bh);
}

// ---- tile+edge: 256x256 upper-tri z@z^T tiles, 1024 threads (16 waves of -
// 64x64 output each -> acc[4][4] = 64 AGPR/thread, same per-wave register
// layout the 128^2 kernel proved fits at 4 waves/SIMD; round-8's spill came
// from acc[4][8]=128 AGPR under a 128-reg cap). Blocks: 2080 -> 528; staging
// bytes/output halved; prologue/epilogue amortized 4x.
__global__ __launch_bounds__(1024, 4)
void tile_edge_kernel(const unsigned short* __restrict__ zb,
                      const int* __restrict__ ei, int E,
                      unsigned int* __restrict__ ht,
                      float* __restrict__ part) {
    // XOR-swizzled unpadded LDS: tile = 256 rows x 8 int4 (BK=64), chunk ch
    // of row r stored at slot ch^(r&7). 2 tiles x 32 KB = 64 KB.
    __shared__ int4 la[256 * 8];
    __shared__ int4 lb[256 * 8];

    const int tid = threadIdx.x;
    const int bid = blockIdx.x;

    // triangular map: bid -> (bi<=bj) over 32x32 tile grid
    // off(bi) = bi*(65-bi)/2 ; row bi holds 32-bi tiles
    int bi = (int)((65.0f - sqrtf(4225.0f - 8.0f * (float)bid)) * 0.5f);
    bi = min(max(bi, 0), 31);
    while ((bi * (65 - bi)) / 2 > bid) --bi;
    while (((bi + 1) * (64 - bi)) / 2 <= bid) ++bi;
    const int bj = bi + (bid - (bi * (65 - bi)) / 2);

    const int wid = tid >> 6, lane = tid & 63;
    const int wr = wid >> 2, wc = wid & 3;      // 4x4 wave grid, 64x64 each
    const int l15 = lane & 15, quad = lane >> 4;
    const int xk = l15 & 7;                     // xor key for fragment reads

    const int4* ga = (const int4*)(zb + (size_t)bi * 256 * MM);
    const int4* gb = (const int4*)(zb + (size_t)bj * 256 * MM);

    f32x4 zero4 = {0.f, 0.f, 0.f, 0.f};
    f32x4 acc[4][4];
    #pragma unroll
    for (int i = 0; i < 4; ++i)
        #pragma unroll
        for (int j = 0; j < 4; ++j) acc[i][j] = zero4;

    const short* sa = (const short*)la;
    const short* sb = (const short*)lb;

    #pragma unroll
    for (int kc = 0; kc < 2; ++kc) {        // K halves of 64
        if (kc) __syncthreads();
        #pragma unroll
        for (int i = 0; i < 2; ++i) {       // stage both tiles, swizzled
            const int c = tid + i * 1024;   // 0..2047
            const int row = c >> 3, ch = c & 7;
            const int sl = ch ^ (row & 7);
            la[row * 8 + sl] = ga[row * 16 + kc * 8 + ch];
            lb[row * 8 + sl] = gb[row * 16 + kc * 8 + ch];
        }
        __syncthreads();
        #pragma unroll
        for (int ks = 0; ks < 2; ++ks) {    // two k=32 MFMA steps
            const int kq = ks * 4 + quad;   // chunk index 0..7 (int4 units)
            bf16x8 af[4], bfr[4];
            #pragma unroll
            for (int t2 = 0; t2 < 4; ++t2) {
                const int ar = wr * 64 + t2 * 16 + l15;
                af[t2]  = *(const bf16x8*)&sa[ar * 64 + ((kq ^ xk) * 8)];
                const int br = wc * 64 + t2 * 16 + l15;
                bfr[t2] = *(const bf16x8*)&sb[br * 64 + ((kq ^ xk) * 8)];
            }
            #pragma unroll
            for (int i = 0; i < 4; ++i)
                #pragma unroll
                for (int j = 0; j < 4; ++j)
                    acc[i][j] = __builtin_amdgcn_mfma_f32_16x16x32_bf16(
                        af[i], bfr[j], acc[i][j], 0, 0, 0);
        }
    }

    // softplus(v) ~= max(v,0) + e - e^2/2, e=exp(-|v|); err <= e^3/3,
    // summed bound ~1e5 << threshold
    float tsum = 0.f;
    if (bi != bj) {
        #pragma unroll
        for (int i = 0; i < 4; ++i)
            #pragma unroll
            for (int j = 0; j < 4; ++j)
                #pragma unroll
                for (int r = 0; r < 4; ++r) {
                    const float v = acc[i][j][r];
                    const float e = __expf(-fabsf(v));
                    tsum += fmaxf(v, 0.f) + e * fmaf(e, -0.5f, 1.f);
                }
    } else {
        const int rbase = wr * 64 + quad * 4;
        const int cbase = wc * 64 + l15;
        #pragma unroll
        for (int i = 0; i < 4; ++i)
            #pragma unroll
            for (int j = 0; j < 4; ++j)
                #pragma unroll
                for (int r = 0; r < 4; ++r)
                    if (cbase + j * 16 > rbase + i * 16 + r) {
                        const float v = acc[i][j][r];
                        const float e = __expf(-fabsf(v));
                        tsum += fmaxf(v, 0.f) + e * fmaf(e, -0.5f, 1.f);
                    }
    }

    tsum = wave_reduce(tsum);
    if (lane == 0)   // per-wave atomic: no barrier needed
        atomicAdd(&part[P_SP + ((bi * 64 + bj + wid * 16) & 63) * 16], tsum);

    // ---- edge tail: blocks [0,128), one edge per thread (128*1024 = E) ---
    if (bid < (E >> 10)) {
        const int e = bid * 1024 + tid;
        float contrib = 0.f;
        const int i = ei[e];
        const int j = ei[E + e];
        if (i != j) {
            const int a = min(i, j), b = max(i, j);
            const unsigned int key = (unsigned int)a * NN + b;  // >=1, <2^26
            unsigned int slot = (key * 2654435761u) & (HSLOTS - 1);
            bool first = false;
            for (;;) {
                const unsigned int old = atomicCAS(&ht[slot], 0u, key);
                if (old == 0u) { first = true; break; }
                if (old == key) break;
                slot = (slot + 1) & (HSLOTS - 1);
            }
            if (first) {
                const uint4* za = (const uint4*)(zb + (size_t)a * MM);
                const uint4* zc = (const uint4*)(zb + (size_t)b * MM);
                float s = 0.f;
                #pragma unroll
                for (int q = 0; q < MM / 8; ++q) {
                    const uint4 ua = za[q], ub = zc[q];
                    s += dotpair(ua.x, ub.x) + dotpair(ua.y, ub.y)
                       + dotpair(ua.z, ub.z) + dotpair(ua.w, ub.w);
                }
                contrib = s;
            }
        }
        contrib = wave_reduce(contrib);
        if (lane == 0)
            atomicAdd(&part[P_EDGE + (bid & 63) * 16], contrib);
    }
}

// ---- final combine: sum 3 x 64 partial slots ----------------------------
__global__ void combine_kernel(const float* __restrict__ part,
                               float* __restrict__ out) {
    const int t = threadIdx.x;   // 64 threads
    float v = part[P_SP + t * 16] - part[P_EDGE + t * 16]
            + 0.001f * part[P_KL + t * 16];
    v = wave_reduce(v);
    if (t == 0) out[0] = v;
}

extern "C" void kernel_launch(void* const* d_in, const int* in_sizes, int n_in,
                              void* d_out, int out_size, void* d_ws, size_t ws_size,
                              hipStream_t stream) {
    const float* x   = (const float*)d_in[0];
    const int* ei    = (const int*)d_in[1];     // int32 on device
    const float* eps = (const float*)d_in[2];
    const float* Wmu = (const float*)d_in[3];
    const float* bmu = (const float*)d_in[4];
    const float* Wsg = (const float*)d_in[5];
    const float* bsg = (const float*)d_in[6];
    float* out = (float*)d_out;
    char* ws = (char*)d_ws;

    float* part = (float*)ws;
    unsigned short* zb = (unsigned short*)(ws + Z_OFF);
    unsigned int* ht = (unsigned int*)(ws + HASH_OFF);
    unsigned short* WmuT = (unsigned short*)(ws + WT_OFF);
    unsigned short* WsgT = (unsigned short*)(ws + WT_OFF + WT_BYTES);
    const int E = in_sizes[1] / 2;

    prep_w<<<128, 256, 0, stream>>>(Wmu, Wsg, WmuT, WsgT, part, ht);
    encoder_mfma<<<NN / 16, 256, 0, stream>>>(x, eps, WmuT, WsgT, bmu, bsg, zb, part);
    tile_edge_kernel<<<NT2, 1024, 0, stream>>>(zb, ei, E, ht, part);
    combine_kernel<<<1, 64, 0, stream>>>(part, out);
}

// Round 11
// 113.822 us; speedup vs baseline: 1.9837x; 1.0610x over previous
//
#include <hip/hip_runtime.h>

#define NN 8192
#define FF 256
#define MM 128
#define HSLOTS 262144   // power of 2, 2x edge count
#define NTILES 2080     // 64*65/2 upper-tri 128x128 tiles

typedef __attribute__((ext_vector_type(8))) short bf16x8;
typedef __attribute__((ext_vector_type(4))) float f32x4;

// ws layout (bytes):
// [0, 16K): partial sums, 3 arrays x 64 slots, 64B apart
// [16K, +2MB): z bf16 [NN][MM]
// [.., +1MB): dedup hash set (u32 keys, 0 = empty; zeroed in prep_w)
// [.., +64KB): WmuT bf16 [MM][FF]   (transposed, K contiguous)
// [.., +64KB): WsgT bf16 [MM][FF]
#define P_KL    0
#define P_EDGE  (64 * 16)
#define P_SP    (128 * 16)
#define Z_OFF   16384
#define Z_BYTES (NN * MM * 2)
#define HASH_OFF (Z_OFF + Z_BYTES)
#define WT_OFF  (HASH_OFF + HSLOTS * 4)
#define WT_BYTES (MM * FF * 2)

__device__ __forceinline__ float wave_reduce(float v) {
    #pragma unroll
    for (int off = 32; off > 0; off >>= 1) v += __shfl_down(v, off);
    return v;
}
__device__ __forceinline__ unsigned short f2bf(float f) {
    unsigned int u = __float_as_uint(f);
    u += 0x7fffu + ((u >> 16) & 1u);   // round to nearest even
    return (unsigned short)(u >> 16);
}
__device__ __forceinline__ int4 pack8(float4 a, float4 b) {
    int4 p;
    p.x = (int)f2bf(a.x) | ((int)f2bf(a.y) << 16);
    p.y = (int)f2bf(a.z) | ((int)f2bf(a.w) << 16);
    p.z = (int)f2bf(b.x) | ((int)f2bf(b.y) << 16);
    p.w = (int)f2bf(b.z) | ((int)f2bf(b.w) << 16);
    return p;
}

// ---- prep: W transpose->bf16, zero partials, zero hash table -------------
__global__ __launch_bounds__(256)
void prep_w(const float* __restrict__ Wmu, const float* __restrict__ Wsg,
            unsigned short* __restrict__ WmuT, unsigned short* __restrict__ WsgT,
            float* __restrict__ part, unsigned int* __restrict__ ht) {
    const int t = blockIdx.x * 256 + threadIdx.x;   // 0..32767
    const int n = t >> 8, f = t & 255;
    WmuT[t] = f2bf(Wmu[f * MM + n]);
    WsgT[t] = f2bf(Wsg[f * MM + n]);
    if (t < 4096) part[t] = 0.f;          // 16 KB of partial slots
    uint4 z4 = {0u, 0u, 0u, 0u};
    ((uint4*)ht)[t * 2]     = z4;         // 32768*2 uint4 = 262144 words
    ((uint4*)ht)[t * 2 + 1] = z4;
}

// ---- encoder: MFMA GEMMs, W-fragments direct from global, 1 barrier ------
#define XP_I4 33   // int4 pitch per x row (32 data + 1 pad)
#define XP_S  264

__global__ __launch_bounds__(256)
void encoder_mfma(const float* __restrict__ x, const float* __restrict__ eps,
                  const unsigned short* __restrict__ WmuT,
                  const unsigned short* __restrict__ WsgT,
                  const float* __restrict__ bmu, const float* __restrict__ bsg,
                  unsigned short* __restrict__ zb, float* __restrict__ part) {
    __shared__ int4 ax[16 * XP_I4];   // 8.4 KB: 16 x-rows, K=256 bf16
    __shared__ float red[4];
    const int tid = threadIdx.x;
    const int wid = tid >> 6, lane = tid & 63;
    const int l15 = lane & 15, quad = lane >> 4;
    const int row0 = blockIdx.x * 16;

    {   // stage 16 rows x 256 cols of x as bf16 (coalesced float4 pairs)
        const int r = tid >> 4, ch = tid & 15;
        const float4* g0 = (const float4*)(x + (size_t)(row0 + r) * FF + ch * 8);
        const float4* g1 = (const float4*)(x + (size_t)(row0 + r) * FF + (ch + 16) * 8);
        ax[r * XP_I4 + ch]      = pack8(g0[0], g0[1]);
        ax[r * XP_I4 + ch + 16] = pack8(g1[0], g1[1]);
    }
    __syncthreads();

    const short* sax = (const short*)ax;
    const int4* wtm = (const int4*)WmuT;   // row n = 32 int4 (K=256)
    const int4* wts = (const int4*)WsgT;

    f32x4 zero4 = {0.f, 0.f, 0.f, 0.f};
    f32x4 accm[2], accl[2];
    accm[0] = accm[1] = accl[0] = accl[1] = zero4;

    #pragma unroll
    for (int ks = 0; ks < 8; ++ks) {       // K = 8 x 32
        const bf16x8 a = *(const bf16x8*)&sax[l15 * XP_S + ks * 32 + quad * 8];
        #pragma unroll
        for (int j = 0; j < 2; ++j) {
            const int n = wid * 32 + j * 16 + l15;
            const bf16x8 bmf = *(const bf16x8*)&wtm[n * 32 + ks * 4 + quad];
            const bf16x8 bsf = *(const bf16x8*)&wts[n * 32 + ks * 4 + quad];
            accm[j] = __builtin_amdgcn_mfma_f32_16x16x32_bf16(a, bmf, accm[j], 0, 0, 0);
            accl[j] = __builtin_amdgcn_mfma_f32_16x16x32_bf16(a, bsf, accl[j], 0, 0, 0);
        }
    }

    // epilogue: C map col=lane&15, row=quad*4+reg [m89]
    float klp = 0.f;
    #pragma unroll
    for (int j = 0; j < 2; ++j) {
        const int col = wid * 32 + j * 16 + l15;
        const float bm = bmu[col], bs = bsg[col];
        #pragma unroll
        for (int r = 0; r < 4; ++r) {
            const int row = row0 + quad * 4 + r;
            const float mu = accm[j][r] + bm;
            const float ls = accl[j][r] + bs;
            const float sg = __expf(ls);
            const float zz = fmaf(sg, eps[(size_t)row * MM + col], mu);
            zb[(size_t)row * MM + col] = f2bf(zz);
            klp += 0.5f * (sg * sg + mu * mu - 1.f) - ls;
        }
    }

    klp = wave_reduce(klp);
    if (lane == 0) red[wid] = klp;
    __syncthreads();
    if (tid == 0)
        atomicAdd(&part[P_KL + (blockIdx.x & 63) * 16],
                  red[0] + red[1] + red[2] + red[3]);
}

// ---- helpers for edge tail ----------------------------------------------
__device__ __forceinline__ float dotpair(unsigned int a, unsigned int b) {
    const float al = __uint_as_float(a << 16);
    const float ah = __uint_as_float(a & 0xffff0000u);
    const float bl = __uint_as_float(b << 16);
    const float bh = __uint_as_float(b & 0xffff0000u);
    return fmaf(al, bl, ah * bh);
}

// ---- tile+edge: triangular-mapped MFMA z@z^T tiles; blocks [0,NE) also ---
// process 256 edges each AFTER their tile (uniform entry: no role branch,
// no per-block fence). Edge latency hides under later blocks' tile compute.
__global__ __launch_bounds__(256, 3)
void tile_edge_kernel(const unsigned short* __restrict__ zb,
                      const int* __restrict__ ei, int E, int NE,
                      unsigned int* __restrict__ ht,
                      float* __restrict__ part) {
    // XOR-swizzled unpadded LDS: tile = 128 rows x 8 int4 (BK=64), chunk ch of
    // row r stored at slot ch^(r&7). 2 tiles x 16 KB = 32 KB.
    __shared__ int4 la[128 * 8];
    __shared__ int4 lb[128 * 8];

    const int tid = threadIdx.x;
    const int bid = blockIdx.x;

    // triangular map: bid -> (bi<=bj) over 64x64 tile grid
    // off(bi) = bi*(129-bi)/2 ; row bi holds 64-bi tiles
    int bi = (int)((129.0f - sqrtf(16641.0f - 8.0f * (float)bid)) * 0.5f);
    bi = min(max(bi, 0), 63);
    while ((bi * (129 - bi)) / 2 > bid) --bi;
    while (((bi + 1) * (128 - bi)) / 2 <= bid) ++bi;
    const int bj = bi + (bid - (bi * (129 - bi)) / 2);

    const int wid = tid >> 6, lane = tid & 63;
    const int wm = wid >> 1, wn = wid & 1;
    const int l15 = lane & 15, quad = lane >> 4;
    const int xk = l15 & 7;                 // xor key for fragment reads

    const int4* ga = (const int4*)(zb + (size_t)bi * 128 * MM);
    const int4* gb = (const int4*)(zb + (size_t)bj * 128 * MM);

    f32x4 zero4 = {0.f, 0.f, 0.f, 0.f};
    f32x4 acc[4][4];
    #pragma unroll
    for (int i = 0; i < 4; ++i)
        #pragma unroll
        for (int j = 0; j < 4; ++j) acc[i][j] = zero4;

    const short* sa = (const short*)la;
    const short* sb = (const short*)lb;

    #pragma unroll
    for (int kc = 0; kc < 2; ++kc) {        // K halves of 64
        if (kc) __syncthreads();
        #pragma unroll
        for (int i = 0; i < 4; ++i) {       // stage both tiles, swizzled
            const int c = tid + i * 256;    // 0..1023
            const int row = c >> 3, ch = c & 7;
            const int sl = ch ^ (row & 7);
            la[row * 8 + sl] = ga[row * 16 + kc * 8 + ch];
            lb[row * 8 + sl] = gb[row * 16 + kc * 8 + ch];
        }
        __syncthreads();
        #pragma unroll
        for (int ks = 0; ks < 2; ++ks) {    // two k=32 MFMA steps
            const int kq = ks * 4 + quad;   // chunk index 0..7 (int4 units)
            bf16x8 af[4], bfr[4];
            #pragma unroll
            for (int t2 = 0; t2 < 4; ++t2) {
                const int ar = wm * 64 + t2 * 16 + l15;
                af[t2]  = *(const bf16x8*)&sa[ar * 64 + ((kq ^ xk) * 8)];
                const int br = wn * 64 + t2 * 16 + l15;
                bfr[t2] = *(const bf16x8*)&sb[br * 64 + ((kq ^ xk) * 8)];
            }
            #pragma unroll
            for (int i = 0; i < 4; ++i)
                #pragma unroll
                for (int j = 0; j < 4; ++j)
                    acc[i][j] = __builtin_amdgcn_mfma_f32_16x16x32_bf16(
                        af[i], bfr[j], acc[i][j], 0, 0, 0);
        }
    }

    // softplus(v) ~= max(v,0) + e - e^2/2, e=exp(-|v|); err <= e^3/3,
    // summed bound ~1e5 << threshold
    float tsum = 0.f;
    if (bi != bj) {
        #pragma unroll
        for (int i = 0; i < 4; ++i)
            #pragma unroll
            for (int j = 0; j < 4; ++j)
                #pragma unroll
                for (int r = 0; r < 4; ++r) {
                    const float v = acc[i][j][r];
                    const float e = __expf(-fabsf(v));
                    tsum += fmaxf(v, 0.f) + e * fmaf(e, -0.5f, 1.f);
                }
    } else {
        const int rbase = wm * 64 + quad * 4;
        const int cbase = wn * 64 + l15;
        #pragma unroll
        for (int i = 0; i < 4; ++i)
            #pragma unroll
            for (int j = 0; j < 4; ++j)
                #pragma unroll
                for (int r = 0; r < 4; ++r)
                    if (cbase + j * 16 > rbase + i * 16 + r) {
                        const float v = acc[i][j][r];
                        const float e = __expf(-fabsf(v));
                        tsum += fmaxf(v, 0.f) + e * fmaf(e, -0.5f, 1.f);
                    }
    }

    tsum = wave_reduce(tsum);
    if (lane == 0)   // per-wave atomic: no barrier needed
        atomicAdd(&part[P_SP + ((bi * 64 + bj + wid * 16) & 63) * 16], tsum);

    // ---- edge tail: first NE blocks (dispatched earliest) do 256 edges ---
    if (bid < NE) {
        const int e = bid * 256 + tid;
        float contrib = 0.f;
        if (e < E) {
            const int i = ei[e];
            const int j = ei[E + e];
            if (i != j) {
                const int a = min(i, j), b = max(i, j);
                const unsigned int key = (unsigned int)a * NN + b;  // >=1, <2^26
                unsigned int slot = (key * 2654435761u) & (HSLOTS - 1);
                bool first = false;
                for (;;) {
                    const unsigned int old = atomicCAS(&ht[slot], 0u, key);
                    if (old == 0u) { first = true; break; }
                    if (old == key) break;
                    slot = (slot + 1) & (HSLOTS - 1);
                }
                if (first) {
                    const uint4* za = (const uint4*)(zb + (size_t)a * MM);
                    const uint4* zc = (const uint4*)(zb + (size_t)b * MM);
                    float s = 0.f;
                    #pragma unroll
                    for (int q = 0; q < MM / 8; ++q) {
                        const uint4 ua = za[q], ub = zc[q];
                        s += dotpair(ua.x, ub.x) + dotpair(ua.y, ub.y)
                           + dotpair(ua.z, ub.z) + dotpair(ua.w, ub.w);
                    }
                    contrib = s;
                }
            }
        }
        contrib = wave_reduce(contrib);
        if ((tid & 63) == 0)
            atomicAdd(&part[P_EDGE + (bid & 63) * 16], contrib);
    }
}

// ---- final combine: sum 3 x 64 partial slots ----------------------------
__global__ void combine_kernel(const float* __restrict__ part,
                               float* __restrict__ out) {
    const int t = threadIdx.x;   // 64 threads
    float v = part[P_SP + t * 16] - part[P_EDGE + t * 16]
            + 0.001f * part[P_KL + t * 16];
    v = wave_reduce(v);
    if (t == 0) out[0] = v;
}

extern "C" void kernel_launch(void* const* d_in, const int* in_sizes, int n_in,
                              void* d_out, int out_size, void* d_ws, size_t ws_size,
                              hipStream_t stream) {
    const float* x   = (const float*)d_in[0];
    const int* ei    = (const int*)d_in[1];     // int32 on device
    const float* eps = (const float*)d_in[2];
    const float* Wmu = (const float*)d_in[3];
    const float* bmu = (const float*)d_in[4];
    const float* Wsg = (const float*)d_in[5];
    const float* bsg = (const float*)d_in[6];
    float* out = (float*)d_out;
    char* ws = (char*)d_ws;

    float* part = (float*)ws;
    unsigned short* zb = (unsigned short*)(ws + Z_OFF);
    unsigned int* ht = (unsigned int*)(ws + HASH_OFF);
    unsigned short* WmuT = (unsigned short*)(ws + WT_OFF);
    unsigned short* WsgT = (unsigned short*)(ws + WT_OFF + WT_BYTES);
    const int E = in_sizes[1] / 2;
    const int NE = (E + 255) / 256;             // 512

    prep_w<<<128, 256, 0, stream>>>(Wmu, Wsg, WmuT, WsgT, part, ht);
    encoder_mfma<<<NN / 16, 256, 0, stream>>>(x, eps, WmuT, WsgT, bmu, bsg, zb, part);
    tile_edge_kernel<<<NTILES, 256, 0, stream>>>(zb, ei, E, NE, ht, part);
    combine_kernel<<<1, 64, 0, stream>>>(part, out);
}